// Round 3
// baseline (67.144 us; speedup 1.0000x reference)
//
#include <hip/hip_runtime.h>

#define E_EDGES 8192
#define KN 32
#define DD 128
#define HH 64
#define XPAD 8          // bf16 row padding: row stride 272 B
#define EPB 4           // edges per block (software-pipelined)
#define NBLK (E_EDGES / EPB)

typedef __attribute__((ext_vector_type(8))) __bf16 bf16x8;
typedef __attribute__((ext_vector_type(4))) __bf16 bf16x4;
typedef __attribute__((ext_vector_type(4))) float f32x4;

// Barrier that does NOT drain vmcnt: LDS ordering only (lgkmcnt) + raw
// s_barrier. Keeps prefetched global->reg loads alive across the barrier.
__device__ __forceinline__ void sync_lds() {
    asm volatile("s_waitcnt lgkmcnt(0)" ::: "memory");
    __builtin_amdgcn_s_barrier();
    __builtin_amdgcn_sched_barrier(0);
}

__global__ __launch_bounds__(256, 4)
void he_attn_kernel(const float* __restrict__ X,
                    const int* __restrict__ idx,
                    const float* __restrict__ W1,
                    const float* __restrict__ b1,
                    const float* __restrict__ W2,
                    const float* __restrict__ b2,
                    float* __restrict__ Zout,
                    float* __restrict__ Bout)
{
    const int tid  = threadIdx.x;
    const int lane = tid & 63;
    const int wv   = tid >> 6;       // wave 0..3
    const int cl   = lane & 15;      // column within 16-wide tile
    const int kg   = lane >> 4;      // k-chunk group 0..3
    const int ebase = blockIdx.x * EPB;

    const int r0 = tid >> 5;         // x-staging: rows r0 + 8*it
    const int c0 = (tid & 31) * 4;   // f32 col within row
    const int j  = wv * 16 + cl;     // W1 row this lane feeds

    __shared__ unsigned short xsb[KN][DD + XPAD];  // bf16 x_he
    __shared__ float wpart[4][KN];
    __shared__ float beta_s[KN];

    // ---------------- prologue: all small per-edge scalars ----------------
    float b1v[EPB], w2v[EPB], b2v[EPB];
    #pragma unroll
    for (int t = 0; t < EPB; ++t) {
        b1v[t] = b1[(size_t)(ebase + t) * HH + j];
        w2v[t] = W2[(size_t)(ebase + t) * HH + j];
        b2v[t] = b2[ebase + t];
    }
    // idx + X + W1 for edge 0; idx for edge 1 (idx heads a dependent chain)
    int rowc[4];
    #pragma unroll
    for (int it = 0; it < 4; ++it) rowc[it] = idx[(size_t)ebase * KN + r0 + 8 * it];
    float4 xr[4];
    #pragma unroll
    for (int it = 0; it < 4; ++it)
        xr[it] = *reinterpret_cast<const float4*>(X + (size_t)rowc[it] * DD + c0);
    float4 wf[8];
    {
        const float* W1r = W1 + ((size_t)ebase * HH + j) * DD;
        #pragma unroll
        for (int q = 0; q < 8; ++q)
            wf[q] = *reinterpret_cast<const float4*>(W1r + (q >> 1) * 32 + kg * 8 + (q & 1) * 4);
    }
    int rown[4];
    #pragma unroll
    for (int it = 0; it < 4; ++it)
        rown[it] = idx[(size_t)(ebase + 1) * KN + r0 + 8 * it];

    #pragma unroll
    for (int t = 0; t < EPB; ++t) {
        const int e = ebase + t;

        // pack W1 fragments (waits wf_t; frees wf for next issue)
        bf16x8 bb[4];
        #pragma unroll
        for (int kc = 0; kc < 4; ++kc) {
            float4 a = wf[2 * kc], b = wf[2 * kc + 1];
            bf16x8 v;
            v[0] = (__bf16)a.x; v[1] = (__bf16)a.y; v[2] = (__bf16)a.z; v[3] = (__bf16)a.w;
            v[4] = (__bf16)b.x; v[5] = (__bf16)b.y; v[6] = (__bf16)b.z; v[7] = (__bf16)b.w;
            bb[kc] = v;
        }

        sync_lds();   // prior iteration's z-phase done reading xsb

        // write x_he tile (waits xr_t)
        #pragma unroll
        for (int it = 0; it < 4; ++it) {
            bf16x4 bv;
            bv[0] = (__bf16)xr[it].x; bv[1] = (__bf16)xr[it].y;
            bv[2] = (__bf16)xr[it].z; bv[3] = (__bf16)xr[it].w;
            *reinterpret_cast<bf16x4*>(&xsb[r0 + 8 * it][c0]) = bv;
        }

        // issue next-edge heavy loads: stay in flight through MFMA+tail
        if (t + 1 < EPB) {
            #pragma unroll
            for (int it = 0; it < 4; ++it)
                xr[it] = *reinterpret_cast<const float4*>(X + (size_t)rown[it] * DD + c0);
            const float* W1r = W1 + ((size_t)(e + 1) * HH + j) * DD;
            #pragma unroll
            for (int q = 0; q < 8; ++q)
                wf[q] = *reinterpret_cast<const float4*>(W1r + (q >> 1) * 32 + kg * 8 + (q & 1) * 4);
        }
        if (t + 2 < EPB) {
            #pragma unroll
            for (int it = 0; it < 4; ++it)
                rown[it] = idx[(size_t)(e + 2) * KN + r0 + 8 * it];
        }

        sync_lds();   // xsb_t ready

        // ---- h-GEMM: 32x64x128 bf16 MFMA ----
        f32x4 acc0 = {0.f, 0.f, 0.f, 0.f}, acc1 = {0.f, 0.f, 0.f, 0.f};
        #pragma unroll
        for (int kc = 0; kc < 4; ++kc) {
            const int ds = kc * 32 + kg * 8;
            bf16x8 a0 = *reinterpret_cast<const bf16x8*>(&xsb[cl][ds]);
            bf16x8 a1 = *reinterpret_cast<const bf16x8*>(&xsb[16 + cl][ds]);
            acc0 = __builtin_amdgcn_mfma_f32_16x16x32_bf16(a0, bb[kc], acc0, 0, 0, 0);
            acc1 = __builtin_amdgcn_mfma_f32_16x16x32_bf16(a1, bb[kc], acc1, 0, 0, 0);
        }

        // ---- epilogue: h = leaky(acc+b1); w-partials via 16-lane reduce ----
        float pk[8];
        #pragma unroll
        for (int r = 0; r < 4; ++r) {
            float h0 = acc0[r] + b1v[t]; h0 = (h0 > 0.f) ? h0 : 0.01f * h0;
            float h1 = acc1[r] + b1v[t]; h1 = (h1 > 0.f) ? h1 : 0.01f * h1;
            pk[r]     = h0 * w2v[t];
            pk[4 + r] = h1 * w2v[t];
        }
        #pragma unroll
        for (int m = 1; m < 16; m <<= 1) {
            #pragma unroll
            for (int q = 0; q < 8; ++q) pk[q] += __shfl_xor(pk[q], m);
        }
        if (cl == 0) {
            #pragma unroll
            for (int r = 0; r < 4; ++r) {
                wpart[wv][kg * 4 + r]      = pk[r];
                wpart[wv][16 + kg * 4 + r] = pk[4 + r];
            }
        }

        sync_lds();

        // ---- softmax over K=32 ----
        if (tid < KN) {
            float v = b2v[t] + wpart[0][tid] + wpart[1][tid] + wpart[2][tid] + wpart[3][tid];
            float mx = v;
            #pragma unroll
            for (int off = 16; off >= 1; off >>= 1) mx = fmaxf(mx, __shfl_xor(mx, off));
            float ex = __expf(v - mx);
            float s = ex;
            #pragma unroll
            for (int off = 16; off >= 1; off >>= 1) s += __shfl_xor(s, off);
            float beta = ex / s;
            beta_s[tid] = beta;
            Bout[(size_t)e * KN + tid] = beta;
        }

        sync_lds();

        // ---- z + tanh(leaky(z)) ----
        if (tid < DD) {
            float z = 0.f;
            #pragma unroll
            for (int k = 0; k < KN; ++k) {
                unsigned int bq = xsb[k][tid];
                z += beta_s[k] * __builtin_bit_cast(float, bq << 16);
            }
            z = (z > 0.f) ? z : 0.01f * z;
            Zout[(size_t)e * DD + tid] = tanhf(z);
        }
    }
}

extern "C" void kernel_launch(void* const* d_in, const int* in_sizes, int n_in,
                              void* d_out, int out_size, void* d_ws, size_t ws_size,
                              hipStream_t stream) {
    const float* X   = (const float*)d_in[0];
    const int*   idx = (const int*)d_in[1];
    const float* W1  = (const float*)d_in[2];
    const float* b1  = (const float*)d_in[3];
    const float* W2  = (const float*)d_in[4];
    const float* b2  = (const float*)d_in[5];
    float* Zout = (float*)d_out;                       // [E, D]
    float* Bout = Zout + (size_t)E_EDGES * DD;         // [E, K]
    (void)in_sizes; (void)n_in; (void)out_size; (void)d_ws; (void)ws_size;
    he_attn_kernel<<<dim3(NBLK), dim3(256), 0, stream>>>(X, idx, W1, b1, W2, b2, Zout, Bout);
}

// Round 4
// 66.455 us; speedup vs baseline: 1.0104x; 1.0104x over previous
//
#include <hip/hip_runtime.h>

#define E_EDGES 8192
#define KN 32
#define DD 128
#define HH 64
#define XSTR (DD + 8)   // ushort row stride: 272 B

typedef __attribute__((ext_vector_type(8))) __bf16 bf16x8;
typedef __attribute__((ext_vector_type(4))) __bf16 bf16x4;
typedef __attribute__((ext_vector_type(4))) float f32x4;

__device__ __forceinline__ float bf2f(unsigned int u) {
    return __builtin_bit_cast(float, u << 16);
}

// Wave-local LDS ordering fence: no s_barrier (waves are independent),
// just drain lgkm + stop compiler reordering. Same-wave DS ops are FIFO.
__device__ __forceinline__ void wave_sync_lds() {
    asm volatile("s_waitcnt lgkmcnt(0)" ::: "memory");
    __builtin_amdgcn_wave_barrier();
}

__global__ __launch_bounds__(256, 4)
void he_attn_kernel(const float* __restrict__ X,
                    const int* __restrict__ idx,
                    const float* __restrict__ W1,
                    const float* __restrict__ b1,
                    const float* __restrict__ W2,
                    const float* __restrict__ b2,
                    float* __restrict__ Zout,
                    float* __restrict__ Bout)
{
    const int tid  = threadIdx.x;
    const int lane = tid & 63;
    const int wv   = tid >> 6;              // wave 0..3 — each owns ONE edge
    const int e    = blockIdx.x * 4 + wv;
    const int cl   = lane & 15;             // MFMA col within 16-tile
    const int kg   = lane >> 4;             // MFMA k-chunk group 0..3

    __shared__ __align__(16) unsigned short xsb[4][KN][XSTR];  // per-wave x_he bf16
    __shared__ __align__(16) float ws[4][KN];                  // per-wave w / beta

    // ---- small per-edge params (head of stream, cheap) ----
    const int iv = idx[(size_t)e * KN + (lane & 31)];
    float b1v[4], w2v[4];
    #pragma unroll
    for (int jt = 0; jt < 4; ++jt) {
        b1v[jt] = b1[(size_t)e * HH + jt * 16 + cl];
        w2v[jt] = W2[(size_t)e * HH + jt * 16 + cl];
    }
    const float b2v = b2[e];

    // ---- W1 N-tile 0 prefetch (8 float4/lane = this wave's 8 KB in flight) ----
    const float* W1e = W1 + (size_t)e * HH * DD;
    float4 wf[8];
    #pragma unroll
    for (int q = 0; q < 8; ++q)
        wf[q] = *reinterpret_cast<const float4*>(
            W1e + (size_t)cl * DD + (q >> 1) * 32 + kg * 8 + (q & 1) * 4);

    // ---- X gather: 16 float4/lane, 2 batches of 8, cvt -> wave-private LDS ----
    const int rb = lane >> 5;               // 0/1
    const int cc = lane & 31;               // float4 col
    #pragma unroll
    for (int hb = 0; hb < 2; ++hb) {
        float4 xr[8];
        #pragma unroll
        for (int q = 0; q < 8; ++q) {
            int row = __shfl(iv, rb + 2 * (hb * 8 + q));
            xr[q] = reinterpret_cast<const float4*>(X)[(size_t)row * (DD / 4) + cc];
        }
        #pragma unroll
        for (int q = 0; q < 8; ++q) {
            bf16x4 bv;
            bv[0] = (__bf16)xr[q].x; bv[1] = (__bf16)xr[q].y;
            bv[2] = (__bf16)xr[q].z; bv[3] = (__bf16)xr[q].w;
            *reinterpret_cast<bf16x4*>(&xsb[wv][rb + 2 * (hb * 8 + q)][cc * 4]) = bv;
        }
    }
    wave_sync_lds();

    // ---- A fragments: 8 x ds_read_b128, kept in regs for all 4 N-tiles ----
    bf16x8 a0[4], a1[4];
    #pragma unroll
    for (int kc = 0; kc < 4; ++kc) {
        a0[kc] = *reinterpret_cast<const bf16x8*>(&xsb[wv][cl][kc * 32 + kg * 8]);
        a1[kc] = *reinterpret_cast<const bf16x8*>(&xsb[wv][16 + cl][kc * 32 + kg * 8]);
    }

    // ---- N-tile loop: cvt W1 -> bb, prefetch next tile, 8 MFMA, fold epi ----
    float pk[8] = {0.f,0.f,0.f,0.f,0.f,0.f,0.f,0.f};
    #pragma unroll
    for (int jt = 0; jt < 4; ++jt) {
        bf16x8 bb[4];
        #pragma unroll
        for (int kc = 0; kc < 4; ++kc) {
            float4 a = wf[2 * kc], b = wf[2 * kc + 1];
            bf16x8 v;
            v[0] = (__bf16)a.x; v[1] = (__bf16)a.y; v[2] = (__bf16)a.z; v[3] = (__bf16)a.w;
            v[4] = (__bf16)b.x; v[5] = (__bf16)b.y; v[6] = (__bf16)b.z; v[7] = (__bf16)b.w;
            bb[kc] = v;
        }
        if (jt < 3) {
            const float* W1r = W1e + (size_t)((jt + 1) * 16 + cl) * DD;
            #pragma unroll
            for (int q = 0; q < 8; ++q)
                wf[q] = *reinterpret_cast<const float4*>(
                    W1r + (q >> 1) * 32 + kg * 8 + (q & 1) * 4);
        }
        f32x4 acc0 = {0.f,0.f,0.f,0.f}, acc1 = {0.f,0.f,0.f,0.f};
        #pragma unroll
        for (int kc = 0; kc < 4; ++kc) {
            acc0 = __builtin_amdgcn_mfma_f32_16x16x32_bf16(a0[kc], bb[kc], acc0, 0, 0, 0);
            acc1 = __builtin_amdgcn_mfma_f32_16x16x32_bf16(a1[kc], bb[kc], acc1, 0, 0, 0);
        }
        // h = leaky(acc + b1[j]); fold h * W2[j] into per-lane k-partials
        #pragma unroll
        for (int r = 0; r < 4; ++r) {
            float h0 = acc0[r] + b1v[jt]; h0 = (h0 > 0.f) ? h0 : 0.01f * h0;
            float h1 = acc1[r] + b1v[jt]; h1 = (h1 > 0.f) ? h1 : 0.01f * h1;
            pk[r]     += h0 * w2v[jt];
            pk[4 + r] += h1 * w2v[jt];
        }
    }
    // reduce over the 16 cl-lanes (j's); kg bits untouched by xor<16
    #pragma unroll
    for (int m = 1; m < 16; m <<= 1) {
        #pragma unroll
        for (int q = 0; q < 8; ++q) pk[q] += __shfl_xor(pk[q], m);
    }
    if (cl == 0) {
        #pragma unroll
        for (int r = 0; r < 4; ++r) {
            ws[wv][kg * 4 + r]      = pk[r];       // k rows 0..15
            ws[wv][16 + kg * 4 + r] = pk[4 + r];   // k rows 16..31
        }
    }
    wave_sync_lds();

    // ---- softmax over K=32 (all 64 lanes, halves duplicate) ----
    {
        const int k = lane & 31;
        float v = ws[wv][k] + b2v;
        float mx = v;
        #pragma unroll
        for (int off = 16; off >= 1; off >>= 1) mx = fmaxf(mx, __shfl_xor(mx, off));
        float ex = __expf(v - mx);
        float s = ex;
        #pragma unroll
        for (int off = 16; off >= 1; off >>= 1) s += __shfl_xor(s, off);
        float beta = ex / s;
        if (lane < 32) {
            ws[wv][k] = beta;                       // program-order after the read
            Bout[(size_t)e * KN + k] = beta;
        }
    }
    wave_sync_lds();

    // ---- z[d] = sum_k beta[k] x[k][d]; each lane owns d = 2*lane, 2*lane+1 ----
    float z0 = 0.f, z1 = 0.f;
    #pragma unroll
    for (int kq = 0; kq < 8; ++kq) {
        f32x4 bq = *reinterpret_cast<const f32x4*>(&ws[wv][kq * 4]);   // broadcast
        #pragma unroll
        for (int r = 0; r < 4; ++r) {
            unsigned int pr = *reinterpret_cast<const unsigned int*>(
                &xsb[wv][kq * 4 + r][2 * lane]);
            z0 += bq[r] * bf2f(pr & 0xffffu);
            z1 += bq[r] * bf2f(pr >> 16);
        }
    }
    z0 = (z0 > 0.f) ? z0 : 0.01f * z0;
    z1 = (z1 > 0.f) ? z1 : 0.01f * z1;
    float2 outv;
    outv.x = tanhf(z0);
    outv.y = tanhf(z1);
    *reinterpret_cast<float2*>(&Zout[(size_t)e * DD + 2 * lane]) = outv;
}

extern "C" void kernel_launch(void* const* d_in, const int* in_sizes, int n_in,
                              void* d_out, int out_size, void* d_ws, size_t ws_size,
                              hipStream_t stream) {
    const float* X   = (const float*)d_in[0];
    const int*   idx = (const int*)d_in[1];
    const float* W1  = (const float*)d_in[2];
    const float* b1  = (const float*)d_in[3];
    const float* W2  = (const float*)d_in[4];
    const float* b2  = (const float*)d_in[5];
    float* Zout = (float*)d_out;                       // [E, D]
    float* Bout = Zout + (size_t)E_EDGES * DD;         // [E, K]
    (void)in_sizes; (void)n_in; (void)out_size; (void)d_ws; (void)ws_size;
    he_attn_kernel<<<dim3(E_EDGES / 4), dim3(256), 0, stream>>>(X, idx, W1, b1, W2, b2, Zout, Bout);
}